// Round 6
// baseline (459.784 us; speedup 1.0000x reference)
//
#include <hip/hip_runtime.h>
#include <hip/hip_bf16.h>

// Problem constants (match reference)
#define NN 100000
#define EE 500000
#define NPB 1024     // pool blocks
#define EB  ((EE + 255) / 256)   // edge blocks, 1 edge/thread

typedef __attribute__((ext_vector_type(8))) __bf16 bf16x8;
typedef __attribute__((ext_vector_type(4))) float f32x4;
typedef __attribute__((ext_vector_type(2))) float f32x2;

// Workspace layout (float units)
// kq8 [N][256] bytes fp8 e4m3 : k(128) | qr(128) per node
// vb  [N][128] bf16
// Wgt [N][8] f32 (atomic-accumulated softmax weights per src node)
// pooledZ[136] f32 (atomic), outv[128], counter, Wf fragment-major bf16, ball[384]
static const long long OFF_KQ8  = 0;
static const long long OFF_VB   = 6400000;
static const long long OFF_WGT  = 12800000;
static const long long OFF_PZ   = 13600000;     // 136
static const long long OFF_OUTV = 13634816;     // 128
static const long long OFF_CNT  = 13634944;
static const long long OFF_WF   = 13635008;     // 24,576 floats
static const long long OFF_BALL = 13659584;     // 384

__device__ inline unsigned short f2bf(float f) {
    unsigned int u = __float_as_uint(f);
    unsigned int r = (u + 0x7FFFu + ((u >> 16) & 1u)) >> 16;   // RNE
    return (unsigned short)r;
}
__device__ inline unsigned int pack2bf(float a, float b) {
    return (unsigned int)f2bf(a) | ((unsigned int)f2bf(b) << 16);
}
#define LOF(u) __uint_as_float((u) << 16)
#define HIF(u) __uint_as_float((u) & 0xffff0000u)

#if __has_builtin(__builtin_amdgcn_cvt_pk_fp8_f32) && __has_builtin(__builtin_amdgcn_cvt_pk_f32_fp8)
#define HW_FP8 1
#endif

// ---- fp8 e4m3fn helpers ----
__device__ inline unsigned char enc_fp8(float f) {
#ifdef HW_FP8
    int p = __builtin_amdgcn_cvt_pk_fp8_f32(f, f, 0, false);
    return (unsigned char)(p & 0xff);
#else
    unsigned int u = __float_as_uint(f);
    unsigned int s = (u >> 24) & 0x80u;
    unsigned int a = u & 0x7fffffffu;
    if (a >= 0x43e80000u) return (unsigned char)(s | 0x7e);
    if (a < 0x3c800000u) {
        float av = __uint_as_float(a);
        unsigned int m = (unsigned int)rintf(av * 512.0f);
        return (unsigned char)(s | m);
    }
    unsigned int base = a - 0x3c000000u;
    unsigned int r = (base + 0x7ffffu + ((base >> 20) & 1u)) >> 20;
    return (unsigned char)(s | r);
#endif
}

#ifndef HW_FP8
__device__ inline float dec1_fp8(unsigned int b) {
    unsigned int s = (b & 0x80u) << 24;
    unsigned int em = b & 0x7fu;
    float v;
    if (em >= 8u) v = __uint_as_float(s | ((em + 960u) << 20));
    else {
        v = (float)em * 0.001953125f;
        v = __uint_as_float(__float_as_uint(v) | s);
    }
    return v;
}
#endif

__device__ inline float dot4_fp8(unsigned int ka, unsigned int qa, float d) {
#ifdef HW_FP8
    f32x2 k0 = __builtin_amdgcn_cvt_pk_f32_fp8((int)ka, false);
    f32x2 k1 = __builtin_amdgcn_cvt_pk_f32_fp8((int)ka, true);
    f32x2 q0 = __builtin_amdgcn_cvt_pk_f32_fp8((int)qa, false);
    f32x2 q1 = __builtin_amdgcn_cvt_pk_f32_fp8((int)qa, true);
    d = fmaf(k0.x, q0.x, d); d = fmaf(k0.y, q0.y, d);
    d = fmaf(k1.x, q1.x, d); d = fmaf(k1.y, q1.y, d);
    return d;
#else
    #pragma unroll
    for (int i = 0; i < 4; ++i)
        d = fmaf(dec1_fp8((ka >> (8*i)) & 0xff), dec1_fp8((qa >> (8*i)) & 0xff), d);
    return d;
#endif
}

// ---------------------------------------------------------------------------
// Prep: fragment-major folded weights Wf + bias ball; zero Wgt/pooledZ/counter.
__global__ void prep(const float* __restrict__ Wk, const float* __restrict__ bk,
                     const float* __restrict__ Wq, const float* __restrict__ bq,
                     const float* __restrict__ Wv, const float* __restrict__ bv,
                     const float* __restrict__ R_att,
                     unsigned short* __restrict__ Wf, float* __restrict__ ball,
                     float* __restrict__ Wgt, float* __restrict__ pooledZ,
                     unsigned int* __restrict__ counter) {
    int j = blockIdx.x;      // 0..383
    int c = threadIdx.x;     // 0..127
    float w;
    if (j < 128) {
        w = Wk[j * 128 + c];
        if (c == 0) ball[j] = bk[j];
    } else if (j < 256) {
        int h = (j - 128) >> 4, d = (j - 128) & 15;
        const float* Rrow = R_att + h * 256 + d * 16;
        float s = 0.f;
        #pragma unroll
        for (int f = 0; f < 16; ++f)
            s = fmaf(Rrow[f], Wq[(h * 16 + f) * 128 + c], s);
        w = s;
        if (c == 0) {
            float sb = 0.f;
            for (int f = 0; f < 16; ++f)
                sb = fmaf(Rrow[f], bq[h * 16 + f], sb);
            ball[j] = sb;
        }
    } else {
        w = Wv[(j - 256) * 128 + c];
        if (c == 0) ball[j] = bv[j - 256];
    }
    int g = j >> 7, wc = (j >> 6) & 1, n = (j >> 4) & 3, lr = j & 15;
    int kk = c >> 5, lk = (c >> 3) & 3, i = c & 7;
    int idx = ((((g * 2 + wc) * 4 + n) * 4 + kk) * 64 + lk * 16 + lr) * 8 + i;
    Wf[idx] = f2bf(w);
    for (int z = j * 128 + c; z < 200000; z += 384 * 128)
        ((float4*)Wgt)[z] = make_float4(0.f, 0.f, 0.f, 0.f);
    if (j == 0 && c == 0) *counter = 0u;
    if (j == 1 && c < 136) pooledZ[c] = 0.f;
}

// ---------------------------------------------------------------------------
// Projection GEMM: 64 rows x 128 cols per block, 4 waves, no input staging.
// g = blockIdx.y: 0,1 -> fp8 k|qr outputs ; 2 -> bf16 v output.
__global__ __launch_bounds__(256) void proj_mfma(const float* __restrict__ x,
                                                 const unsigned short* __restrict__ Wf,
                                                 const float* __restrict__ ball,
                                                 unsigned char* __restrict__ kq8,
                                                 unsigned char* __restrict__ vb) {
    __shared__ __align__(16) char cs[16384];
    int tid = threadIdx.x;
    int lane = tid & 63, wv = tid >> 6, wr = wv >> 1, wc = wv & 1;
    int lrow = lane & 15, lk = lane >> 4;
    long long row0 = (long long)blockIdx.x * 64;
    int g = blockIdx.y;
    int col0 = g * 128;

    const float* xr[2];
    #pragma unroll
    for (int m = 0; m < 2; ++m) {
        long long gr = row0 + wr * 32 + m * 16 + lrow;
        if (gr >= NN) gr = NN - 1;
        xr[m] = x + gr * 128;
    }
    const unsigned short* bfb = Wf + (size_t)((g * 2 + wc) * 16) * 512 + lane * 8;

    f32x4 acc[2][4];
    #pragma unroll
    for (int m = 0; m < 2; ++m)
        #pragma unroll
        for (int n = 0; n < 4; ++n)
            acc[m][n] = f32x4{0.f, 0.f, 0.f, 0.f};

    #pragma unroll
    for (int kk = 0; kk < 4; ++kk) {
        bf16x8 a[2], b[4];
        #pragma unroll
        for (int m = 0; m < 2; ++m) {
            const float4* p = (const float4*)(xr[m] + (kk * 4 + lk) * 8);
            float4 u0 = p[0], u1 = p[1];
            union { uint4 u; bf16x8 v; } cv;
            cv.u.x = pack2bf(u0.x, u0.y); cv.u.y = pack2bf(u0.z, u0.w);
            cv.u.z = pack2bf(u1.x, u1.y); cv.u.w = pack2bf(u1.z, u1.w);
            a[m] = cv.v;
        }
        #pragma unroll
        for (int n = 0; n < 4; ++n)
            b[n] = *(const bf16x8*)(bfb + (size_t)(n * 4 + kk) * 512);
        #pragma unroll
        for (int m = 0; m < 2; ++m)
            #pragma unroll
            for (int n = 0; n < 4; ++n)
                acc[m][n] = __builtin_amdgcn_mfma_f32_16x16x32_bf16(a[m], b[n], acc[m][n], 0, 0, 0);
    }

    float bias[4];
    #pragma unroll
    for (int n = 0; n < 4; ++n) bias[n] = ball[col0 + wc * 64 + n * 16 + lrow];

    if (g < 2) {
        unsigned char* C = (unsigned char*)cs;   // [64][128] fp8
        #pragma unroll
        for (int m = 0; m < 2; ++m) {
            int rb = wr * 32 + m * 16 + lk * 4;
            #pragma unroll
            for (int n = 0; n < 4; ++n) {
                int cb = wc * 64 + n * 16 + lrow;
                #pragma unroll
                for (int r = 0; r < 4; ++r)
                    C[(rb + r) * 128 + cb] = enc_fp8(acc[m][n][r] + bias[n]);
            }
        }
        __syncthreads();
        #pragma unroll
        for (int it = 0; it < 2; ++it) {
            int c = tid + it * 256;
            int r = c >> 3, sl = c & 7;
            long long gr = row0 + r;
            if (gr < NN)
                *(uint4*)(kq8 + gr * 256 + col0 + sl * 16) = *(const uint4*)(C + r * 128 + sl * 16);
        }
    } else {
        unsigned short* C = (unsigned short*)cs;  // [64][128] bf16
        #pragma unroll
        for (int m = 0; m < 2; ++m) {
            int rb = wr * 32 + m * 16 + lk * 4;
            #pragma unroll
            for (int n = 0; n < 4; ++n) {
                int cb = wc * 64 + n * 16 + lrow;
                #pragma unroll
                for (int r = 0; r < 4; ++r)
                    C[(rb + r) * 128 + cb] = f2bf(acc[m][n][r] + bias[n]);
            }
        }
        __syncthreads();
        #pragma unroll
        for (int it = 0; it < 4; ++it) {
            int c = tid + it * 256;
            int r = c >> 4, sl = c & 15;
            long long gr = row0 + r;
            if (gr < NN)
                *(uint4*)(vb + gr * 256 + sl * 16) = *(const uint4*)((const char*)C + r * 256 + sl * 16);
        }
    }
}

// ---------------------------------------------------------------------------
// Edge pass: one edge per thread, all 8 heads. Full 128B k-row (src) and
// qr-row (dst) loads -> 100% cache-line utilization. 8 atomics into Wgt[src].
__global__ __launch_bounds__(256) void edge_all(const int* __restrict__ ei,
                                                const unsigned char* __restrict__ kq8,
                                                const float* __restrict__ R_pri,
                                                float* __restrict__ Wgt) {
    __shared__ unsigned int pr[256];
    __shared__ float rps[8];
    int tid = threadIdx.x;
    pr[tid] = ((const unsigned int*)ei)[2 * tid + 1];
    if (tid < 8) rps[tid] = R_pri[tid] * 0.25f;
    __syncthreads();
    for (int st = 128; st > 0; st >>= 1) {
        if (tid < st) pr[tid] |= pr[tid + st];
        __syncthreads();
    }
    bool is64 = (pr[0] == 0u);
    int e = blockIdx.x * 256 + tid;
    if (e >= EE) return;
    int sn, dn;
    if (is64) { sn = ei[2 * e]; dn = ei[2 * (EE + e)]; }
    else      { sn = ei[e];     dn = ei[EE + e]; }
    const uint4* kp = (const uint4*)(kq8 + (size_t)sn * 256);
    const uint4* qp = (const uint4*)(kq8 + (size_t)dn * 256 + 128);
    uint4 kw[8], qw[8];
    #pragma unroll
    for (int h = 0; h < 8; ++h) { kw[h] = kp[h]; qw[h] = qp[h]; }
    #pragma unroll
    for (int h = 0; h < 8; ++h) {
        float d = 0.f;
        d = dot4_fp8(kw[h].x, qw[h].x, d); d = dot4_fp8(kw[h].y, qw[h].y, d);
        d = dot4_fp8(kw[h].z, qw[h].z, d); d = dot4_fp8(kw[h].w, qw[h].w, d);
        float w = __expf(d * rps[h]);
        atomicAdd(&Wgt[(size_t)sn * 8 + h], w);
    }
}

// ---------------------------------------------------------------------------
// Dense pool: wave-wide uint4 loads (4 nodes/iter), shfl reduce, atomicAdd
// into global pooledZ[136]; last block finalizes R_msg -> Wa -> alpha -> outv.
__global__ __launch_bounds__(256) void pool_fin(const float* __restrict__ Wgt,
                                                const unsigned char* __restrict__ vb,
                                                float* __restrict__ pooledZ,
                                                unsigned int* __restrict__ counter,
                                                const float* __restrict__ R_msg,
                                                const float* __restrict__ Wa,
                                                const float* __restrict__ ba,
                                                const float* __restrict__ skip,
                                                float* __restrict__ outv) {
    int tid = threadIdx.x;
    int wv = tid >> 6, l = tid & 63;
    int grp = l & 15, sub = l >> 4;   // grp: 8-col group; sub: node-in-quad
    int h = grp >> 1;
    float acc[8] = {0.f, 0.f, 0.f, 0.f, 0.f, 0.f, 0.f, 0.f};
    float zacc = 0.f;
    for (int n0 = blockIdx.x * 16 + wv * 4; n0 < NN; n0 += NPB * 16) {
        int node = n0 + sub;
        if (node < NN) {
            uint4 vv = *(const uint4*)(vb + (size_t)node * 256 + grp * 16);
            float w = Wgt[(size_t)node * 8 + h];
            acc[0] = fmaf(w, LOF(vv.x), acc[0]); acc[1] = fmaf(w, HIF(vv.x), acc[1]);
            acc[2] = fmaf(w, LOF(vv.y), acc[2]); acc[3] = fmaf(w, HIF(vv.y), acc[3]);
            acc[4] = fmaf(w, LOF(vv.z), acc[4]); acc[5] = fmaf(w, HIF(vv.z), acc[5]);
            acc[6] = fmaf(w, LOF(vv.w), acc[6]); acc[7] = fmaf(w, HIF(vv.w), acc[7]);
            if ((grp & 1) == 0) zacc += w;
        }
    }
    // combine the 4 sub-lanes (bits 4,5 of lane id)
    #pragma unroll
    for (int off = 16; off <= 32; off <<= 1) {
        #pragma unroll
        for (int j = 0; j < 8; ++j) acc[j] += __shfl_xor(acc[j], off);
        zacc += __shfl_xor(zacc, off);
    }
    __shared__ float sm[4][16][8];
    __shared__ float smz[4][8];
    if (l < 16) {
        #pragma unroll
        for (int j = 0; j < 8; ++j) sm[wv][l][j] = acc[j];
        if ((l & 1) == 0) smz[wv][l >> 1] = zacc;
    }
    __syncthreads();
    if (tid < 128) {
        int gg = tid >> 3, j = tid & 7;
        float s = sm[0][gg][j] + sm[1][gg][j] + sm[2][gg][j] + sm[3][gg][j];
        atomicAdd(&pooledZ[tid], s);   // col = grp*8 + j == tid
    }
    if (tid < 8) {
        float z = smz[0][tid] + smz[1][tid] + smz[2][tid] + smz[3][tid];
        atomicAdd(&pooledZ[128 + tid], z);
    }
    __threadfence();
    __shared__ int amLast;
    if (tid == 0) amLast = (atomicAdd(counter, 1u) == NPB - 1) ? 1 : 0;
    __syncthreads();
    if (!amLast) return;

    // coherent reads of the accumulated values
    __shared__ float poolZ[136];
    if (tid < 136) poolZ[tid] = atomicAdd(&pooledZ[tid], 0.f);
    __syncthreads();
    __shared__ float pn[128];
    if (tid < 128) pn[tid] = poolZ[tid] / poolZ[128 + (tid >> 4)];
    __syncthreads();
    __shared__ float msg[128];
    if (tid < 128) {
        int hh = tid >> 4, f = tid & 15;
        float s = 0.f;
        #pragma unroll
        for (int d2 = 0; d2 < 16; ++d2)
            s = fmaf(pn[hh * 16 + d2], R_msg[hh * 256 + d2 * 16 + f], s);
        msg[tid] = s;
    }
    __syncthreads();
    if (tid < 128) {
        float s = ba[tid];
        for (int j = 0; j < 128; ++j) s = fmaf(Wa[tid * 128 + j], msg[j], s);
        float alpha = 1.f / (1.f + __expf(-skip[0]));
        outv[tid] = s * alpha;
    }
}

// ---------------------------------------------------------------------------
__global__ __launch_bounds__(256) void broadcast_out(const float* __restrict__ x,
                                                     const float* __restrict__ outv,
                                                     const float* __restrict__ skip,
                                                     float* __restrict__ out) {
    float alpha = 1.f / (1.f + __expf(-skip[0]));
    float beta = 1.f - alpha;
    const int total4 = NN * 128 / 4;
    for (int i = blockIdx.x * blockDim.x + threadIdx.x; i < total4;
         i += gridDim.x * blockDim.x) {
        float4 xv = ((const float4*)x)[i];
        int c4 = i & 31;
        float4 ov = ((const float4*)outv)[c4];
        float4 r;
        r.x = ov.x + beta * xv.x;
        r.y = ov.y + beta * xv.y;
        r.z = ov.z + beta * xv.z;
        r.w = ov.w + beta * xv.w;
        ((float4*)out)[i] = r;
    }
}

// ---------------------------------------------------------------------------
extern "C" void kernel_launch(void* const* d_in, const int* in_sizes, int n_in,
                              void* d_out, int out_size, void* d_ws, size_t ws_size,
                              hipStream_t stream) {
    const float* x      = (const float*)d_in[0];
    const int*   ei     = (const int*)d_in[1];
    const float* Wk     = (const float*)d_in[2];
    const float* bk     = (const float*)d_in[3];
    const float* Wq     = (const float*)d_in[4];
    const float* bq     = (const float*)d_in[5];
    const float* Wv     = (const float*)d_in[6];
    const float* bv     = (const float*)d_in[7];
    const float* Wa     = (const float*)d_in[8];
    const float* ba     = (const float*)d_in[9];
    const float* R_att  = (const float*)d_in[10];
    const float* R_msg  = (const float*)d_in[11];
    const float* R_pri  = (const float*)d_in[12];
    const float* skip   = (const float*)d_in[13];
    float* out = (float*)d_out;
    float* ws  = (float*)d_ws;

    unsigned char* kq8 = (unsigned char*)(ws + OFF_KQ8);
    unsigned char* vbp = (unsigned char*)(ws + OFF_VB);
    float* Wgt   = ws + OFF_WGT;
    float* pz    = ws + OFF_PZ;
    float* outv  = ws + OFF_OUTV;
    unsigned int* counter = (unsigned int*)(ws + OFF_CNT);
    unsigned short* Wf = (unsigned short*)(ws + OFF_WF);
    float* ball  = ws + OFF_BALL;

    prep<<<384, 128, 0, stream>>>(Wk, bk, Wq, bq, Wv, bv, R_att, Wf, ball, Wgt, pz, counter);
    dim3 gg((NN + 63) / 64, 3);
    proj_mfma<<<gg, 256, 0, stream>>>(x, Wf, ball, kq8, vbp);
    edge_all<<<EB, 256, 0, stream>>>(ei, kq8, R_pri, Wgt);
    pool_fin<<<NPB, 256, 0, stream>>>(Wgt, vbp, pz, counter, R_msg, Wa, ba, skip, outv);
    broadcast_out<<<2048, 256, 0, stream>>>(x, outv, skip, out);
}